// Round 2
// baseline (413.490 us; speedup 1.0000x reference)
//
#include <hip/hip_runtime.h>
#include <hip/hip_cooperative_groups.h>
#include <math.h>

namespace cg = cooperative_groups;

// CALayer: out = x * sigmoid(w2 @ leakyrelu(w1 @ mean(x,HW) + b1) + b2)
// B=8, C=256, H=W=128, Cs=16
#define Bn 8
#define Cn 256
#define CSn 16
#define HWn 16384
#define PL4 4096            // float4 per plane
#define NEG_SLOPE 0.2f
#define NBLK 1024           // 2 planes per block; 4 blocks/CU co-resident

__global__ __launch_bounds__(256, 4) void fused_kernel(
    const float* __restrict__ x,  const float* __restrict__ w1,
    const float* __restrict__ b1, const float* __restrict__ w2,
    const float* __restrict__ b2, float* __restrict__ out,
    float* __restrict__ y) {         // y = ws scratch [B*C]
    const int t = threadIdx.x;
    const int bc0 = blockIdx.x * 2;  // two consecutive planes, same batch b
    const float4* p0 = (const float4*)x + (size_t)bc0 * PL4;
    const float4* p1 = p0 + PL4;

    // ---- Phase 1: pool both planes ----
    float s0 = 0.f, s1 = 0.f;
    #pragma unroll 4
    for (int i = 0; i < PL4 / 256; ++i) {
        float4 a = p0[t + i * 256];
        float4 b = p1[t + i * 256];
        s0 += (a.x + a.y) + (a.z + a.w);
        s1 += (b.x + b.y) + (b.z + b.w);
    }
    #pragma unroll
    for (int off = 32; off; off >>= 1) {
        s0 += __shfl_down(s0, off, 64);
        s1 += __shfl_down(s1, off, 64);
    }
    __shared__ float sm0[4], sm1[4];
    const int lane = t & 63, wid = t >> 6;
    if (lane == 0) { sm0[wid] = s0; sm1[wid] = s1; }
    __syncthreads();
    if (t == 0) {
        y[bc0]     = (sm0[0] + sm0[1] + sm0[2] + sm0[3]) * (1.f / (float)HWn);
        y[bc0 + 1] = (sm1[0] + sm1[1] + sm1[2] + sm1[3]) * (1.f / (float)HWn);
        __threadfence();
    }

    // ---- Phase 2: grid-wide sync (all y[b,c] visible) ----
    cg::this_grid().sync();

    // ---- Phase 3: gate for this block's two channels (redundant per block) ----
    const int b = bc0 >> 8;          // batch index (256 planes per batch)
    __shared__ float part[16 * 17];
    __shared__ float y1s[16];
    __shared__ float gv[2];
    {
        const int s = t >> 4, j = t & 15;
        const float* yb = y  + b * Cn + j * 16;
        const float* wr = w1 + s * Cn + j * 16;
        float p = 0.f;
        #pragma unroll
        for (int k = 0; k < 16; ++k) p += yb[k] * wr[k];
        part[s * 17 + j] = p;
    }
    __syncthreads();
    if (t < 16) {
        float acc = b1[t];
        #pragma unroll
        for (int j = 0; j < 16; ++j) acc += part[t * 17 + j];
        y1s[t] = (acc >= 0.f) ? acc : NEG_SLOPE * acc;
    }
    __syncthreads();
    if (t < 2) {
        const int c = (bc0 + t) & (Cn - 1);
        float acc = b2[c];
        #pragma unroll
        for (int s = 0; s < CSn; ++s) acc += y1s[s] * w2[c * CSn + s];
        gv[t] = 1.f / (1.f + __expf(-acc));
    }
    __syncthreads();
    const float g0 = gv[0], g1 = gv[1];

    // ---- Phase 4: rescale the same planes (same-XCD L2/L3 re-read) ----
    float4* o0 = (float4*)out + (size_t)bc0 * PL4;
    float4* o1 = o0 + PL4;
    #pragma unroll 4
    for (int i = 0; i < PL4 / 256; ++i) {
        float4 a  = p0[t + i * 256];
        float4 b4 = p1[t + i * 256];
        a.x *= g0;  a.y *= g0;  a.z *= g0;  a.w *= g0;
        b4.x *= g1; b4.y *= g1; b4.z *= g1; b4.w *= g1;
        o0[t + i * 256] = a;
        o1[t + i * 256] = b4;
    }
}

extern "C" void kernel_launch(void* const* d_in, const int* in_sizes, int n_in,
                              void* d_out, int out_size, void* d_ws, size_t ws_size,
                              hipStream_t stream) {
    const float* x  = (const float*)d_in[0];
    const float* w1 = (const float*)d_in[1];
    const float* b1 = (const float*)d_in[2];
    const float* w2 = (const float*)d_in[3];
    const float* b2 = (const float*)d_in[4];
    float* out = (float*)d_out;
    float* y   = (float*)d_ws;      // [B*C] = 2048 floats

    void* args[] = {(void*)&x, (void*)&w1, (void*)&b1, (void*)&w2,
                    (void*)&b2, (void*)&out, (void*)&y};
    hipLaunchCooperativeKernel((void*)fused_kernel, dim3(NBLK), dim3(256),
                               args, 0, stream);
}

// Round 3
// 258.166 us; speedup vs baseline: 1.6016x; 1.6016x over previous
//
#include <hip/hip_runtime.h>
#include <math.h>

// CALayer: out = x * sigmoid(w2 @ leakyrelu(w1 @ mean(x,HW) + b1) + b2)
// B=8, C=256, H=W=128, Cs=16
#define Bn 8
#define Cn 256
#define CSn 16
#define HWn 16384
#define PL4 4096            // float4 per plane
#define NEG_SLOPE 0.2f

typedef float f4v __attribute__((ext_vector_type(4)));

// ---------------- Kernel 1: global average pool, one block per (b,c) plane ----
__global__ __launch_bounds__(256) void pool_kernel(const float* __restrict__ x,
                                                   float* __restrict__ y) {
    const int bc = blockIdx.x;
    const f4v* xp = (const f4v*)x + (size_t)bc * PL4;
    const int t = threadIdx.x;
    float sum = 0.f;
    #pragma unroll
    for (int i = 0; i < 16; ++i) {
        f4v v = xp[t + i * 256];
        sum += (v.x + v.y) + (v.z + v.w);
    }
    #pragma unroll
    for (int off = 32; off; off >>= 1)
        sum += __shfl_down(sum, off, 64);
    __shared__ float sm[4];
    if ((t & 63) == 0) sm[t >> 6] = sum;
    __syncthreads();
    if (t == 0)
        y[bc] = (sm[0] + sm[1] + sm[2] + sm[3]) * (1.f / (float)HWn);
}

// ---------------- Kernel 2: redundant per-block gate + channel scale ----------
__global__ __launch_bounds__(256) void scale_kernel(const float* __restrict__ x,
                                                    const float* __restrict__ y,
                                                    const float* __restrict__ w1,
                                                    const float* __restrict__ b1,
                                                    const float* __restrict__ w2,
                                                    const float* __restrict__ b2,
                                                    float* __restrict__ out) {
    const int bc = blockIdx.x;
    const int b = bc >> 8, c = bc & (Cn - 1);
    const int t = threadIdx.x;

    // ---- gate: y1[s] = leakyrelu(b1[s] + y[b,:]·w1[s,:]); g = sigmoid(b2[c]+y1·w2[c,:])
    __shared__ float part[CSn * 17];
    __shared__ float y1s[CSn];
    __shared__ float gsh;
    {
        const int s = t >> 4, j = t & 15;            // 16 partials per squeeze-row
        const float* yb = y  + b * Cn + j * 16;
        const float* wr = w1 + s * Cn + j * 16;
        float p = 0.f;
        #pragma unroll
        for (int k = 0; k < 16; ++k) p += yb[k] * wr[k];
        part[s * 17 + j] = p;
    }
    __syncthreads();
    if (t < CSn) {
        float a = b1[t];
        #pragma unroll
        for (int j = 0; j < 16; ++j) a += part[t * 17 + j];
        y1s[t] = (a >= 0.f) ? a : NEG_SLOPE * a;
    }
    __syncthreads();
    if (t == 0) {
        float a = b2[c];
        #pragma unroll
        for (int s = 0; s < CSn; ++s) a += y1s[s] * w2[c * CSn + s];
        gsh = 1.f / (1.f + __expf(-a));
    }
    __syncthreads();
    const float g = gsh;

    // ---- scale this plane: x re-read should hit L3; nt stores avoid evicting x
    const f4v* xp = (const f4v*)x + (size_t)bc * PL4;
    f4v* op = (f4v*)out + (size_t)bc * PL4;
    #pragma unroll
    for (int i = 0; i < 16; ++i) {
        f4v v = xp[t + i * 256];
        v *= g;
        __builtin_nontemporal_store(v, &op[t + i * 256]);
    }
}

extern "C" void kernel_launch(void* const* d_in, const int* in_sizes, int n_in,
                              void* d_out, int out_size, void* d_ws, size_t ws_size,
                              hipStream_t stream) {
    const float* x  = (const float*)d_in[0];
    const float* w1 = (const float*)d_in[1];
    const float* b1 = (const float*)d_in[2];
    const float* w2 = (const float*)d_in[3];
    const float* b2 = (const float*)d_in[4];
    float* out = (float*)d_out;
    float* y   = (float*)d_ws;      // [B*C] = 2048 floats

    pool_kernel<<<Bn * Cn, 256, 0, stream>>>(x, y);
    scale_kernel<<<Bn * Cn, 256, 0, stream>>>(x, y, w1, b1, w2, b2, out);
}